// Round 6
// baseline (69.945 us; speedup 1.0000x reference)
//
#include <hip/hip_runtime.h>
#include <math.h>

#define BATCH 16
#define SEQ   2048
#define EMB   1024
#define HD    64
#define NROWS (BATCH*SEQ)

typedef __attribute__((ext_vector_type(8))) short short8;
typedef __attribute__((ext_vector_type(4))) float f32x4;

// XOR-swizzle 16B granules within a row (T2): 128B rows use row&7, 256B rows row&15
#define SWZ(byte, row)   ((byte) ^ (((row) & 7) << 4))
#define SWZ16(byte, row) ((byte) ^ (((row) & 15) << 4))

__device__ __forceinline__ ushort f2bf(float f) {
    union { float f; unsigned u; } c; c.f = f;
    return (ushort)((c.u + 0x7FFF + ((c.u >> 16) & 1)) >> 16);
}

// async global->LDS, 16B per lane; LDS dest = wave-uniform base + lane*16
__device__ __forceinline__ void gload_lds16(const void* g, void* l) {
    __builtin_amdgcn_global_load_lds(
        (const __attribute__((address_space(1))) void*)g,
        (__attribute__((address_space(3))) void*)l, 16, 0, 0);
}

// ------------- kernel 0: W[e][c] (fp32) -> wt16[c192][e] (bf16) -------------
__global__ void k_transpose_w(const float* __restrict__ Wq,
                              const float* __restrict__ Wk,
                              const float* __restrict__ Wv,
                              ushort* __restrict__ wt) {
    int idx  = blockIdx.x * 256 + threadIdx.x;   // 192*1024
    int c192 = idx >> 10;
    int e    = idx & 1023;
    const float* W = (c192 < 64) ? Wq : (c192 < 128 ? Wk : Wv);
    wt[idx] = f2bf(W[e * HD + (c192 & 63)]);
}

// ------------- kernel 1: QKV projection v3 (counted-vmcnt pipeline) -------------
// Row-partitioned waves: wave w owns 16 x-rows, computes all 192 cols.
// x: direct global fp32 reads, cvt at use. wt: LDS dbuf via global_load_lds.
// Per chunk per wave: exactly 10 VMEM ops (6 DMA + 4 x) -> s_waitcnt vmcnt(10)
// + raw s_barrier keeps next chunk's loads in flight ACROSS the barrier.
__global__ __launch_bounds__(256)
void k_qkv_proj(const float* __restrict__ x, const ushort* __restrict__ wt,
                ushort* __restrict__ qkv, ushort* __restrict__ vt) {
    __shared__ short8 smem[49152 / 16];
    char* base = (char*)smem;                    // 2 x 24KB wt buffers
    const int t = threadIdx.x, lane = t & 63, w = t >> 6;
    const int l15 = lane & 15, lg = lane >> 4;
    const int row0 = blockIdx.x * 64;
    const float* xrowp = x + (size_t)(row0 + w * 16 + l15) * EMB;  // lane's x row

    f32x4 acc[12];
    #pragma unroll
    for (int mi = 0; mi < 12; ++mi) acc[mi] = (f32x4){0.f, 0.f, 0.f, 0.f};

    float4 xc[4], xn[4];                         // cur/next chunk: 2 s x 2 float4

    auto stage_w = [&](int ch, int buf) {        // 6 VMEM ops
        char* wb = base + buf * 24576;
        #pragma unroll
        for (int i = 0; i < 6; ++i) {
            int r = (w * 6 + i) * 8 + (lane >> 3);
            int j = (lane & 7) ^ (r & 7);
            gload_lds16(&wt[(size_t)r * EMB + ch * 64 + j * 8],
                        wb + (w * 6 + i) * 1024);
        }
    };
    auto load_x = [&](int ch, float4* xr) {      // 4 VMEM ops
        #pragma unroll
        for (int s = 0; s < 2; ++s) {
            const float* p = xrowp + ch * 64 + s * 32 + lg * 8;
            xr[s * 2 + 0] = *(const float4*)(p);
            xr[s * 2 + 1] = *(const float4*)(p + 4);
        }
    };

    stage_w(0, 0); load_x(0, xc);
    #pragma unroll 2
    for (int ch = 0; ch < 16; ++ch) {
        int cur = ch & 1;
        if (ch < 15) {
            stage_w(ch + 1, cur ^ 1); load_x(ch + 1, xn);
            asm volatile("s_waitcnt vmcnt(10)" ::: "memory");  // cur's 10 landed
        } else {
            asm volatile("s_waitcnt vmcnt(0)" ::: "memory");
        }
        __builtin_amdgcn_sched_barrier(0);
        __builtin_amdgcn_s_barrier();            // BAR1: cross-wave DMA visibility
        char* wb = base + cur * 24576;
        #pragma unroll
        for (int s = 0; s < 2; ++s) {
            const float* xp = (const float*)&xc[s * 2];
            short8 xf;
            #pragma unroll
            for (int e = 0; e < 8; ++e) xf[e] = (short)f2bf(xp[e]);
            __builtin_amdgcn_s_setprio(1);
            #pragma unroll
            for (int mi = 0; mi < 12; ++mi) {
                int cr = mi * 16 + l15;
                short8 wf = *(short8*)(wb + SWZ(cr * 128 + s * 64 + lg * 16, cr));
                acc[mi] = (mi < 8)
                    ? __builtin_amdgcn_mfma_f32_16x16x32_bf16(wf, xf, acc[mi], 0, 0, 0)
                    : __builtin_amdgcn_mfma_f32_16x16x32_bf16(xf, wf, acc[mi], 0, 0, 0);
            }
            __builtin_amdgcn_s_setprio(0);
        }
        if (ch < 15) {
            #pragma unroll
            for (int i = 0; i < 4; ++i) xc[i] = xn[i];
        }
        __builtin_amdgcn_sched_barrier(0);
        __builtin_amdgcn_s_barrier();            // BAR2: readers done before overwrite
    }

    // epilogue: LDS transposes -> coalesced stores (reuse wt LDS, buf0 region)
    char* qkb = base;          // [64 xrow][128 c] bf16, 256B rows, SWZ16
    char* vtb = base + 16384;  // [64 hd][64 key] bf16, 128B rows, SWZ
    const float qscale = 0.125f * 1.44269504f;   // fold 1/sqrt(64)*log2(e) into Q
    #pragma unroll
    for (int mi = 0; mi < 12; ++mi) {
        ushort4 o;
        if (mi < 8) {                            // Q/K: rows of D = c, col = xrow
            float sc = (mi < 4) ? qscale : 1.0f;
            o.x = f2bf(acc[mi][0] * sc); o.y = f2bf(acc[mi][1] * sc);
            o.z = f2bf(acc[mi][2] * sc); o.w = f2bf(acc[mi][3] * sc);
            int xrow = w * 16 + l15, c = mi * 16 + lg * 4;
            *(ushort4*)(qkb + SWZ16(xrow * 256 + c * 2, xrow)) = o;
        } else {                                 // V: D[key][hd] (already V^T)
            o.x = f2bf(acc[mi][0]); o.y = f2bf(acc[mi][1]);
            o.z = f2bf(acc[mi][2]); o.w = f2bf(acc[mi][3]);
            int hd = (mi - 8) * 16 + l15, key = w * 16 + lg * 4;
            *(ushort4*)(vtb + SWZ(hd * 128 + key * 2, hd)) = o;
        }
    }
    __syncthreads();
    const int b = row0 >> 11, r0b = row0 & 2047;
    #pragma unroll
    for (int i = 0; i < 4; ++i) {                // Q/K: 1024 granules
        int idx = t + i * 256;
        int r = idx >> 4, g = idx & 15;
        short8 v = *(short8*)(qkb + SWZ16(r * 256 + g * 16, r));
        int c0 = g * 8, m = c0 >> 6, c = c0 & 63;
        *(short8*)&qkv[((size_t)m * NROWS + row0 + r) * HD + c] = v;
    }
    #pragma unroll
    for (int i = 0; i < 2; ++i) {                // V^T: 512 granules
        int idx = t + i * 256;
        int hd = idx >> 3, g = idx & 7;
        short8 v = *(short8*)(vtb + SWZ(hd * 128 + g * 16, hd));
        *(short8*)&vt[((size_t)b * HD + hd) * SEQ + r0b + g * 8] = v;
    }
}

// ------------- kernel 2: causal flash attention, counted-vmcnt pipeline -------------
// QB=64, KB=128 pair-steps. Per step per wave: exactly 8 VMEM DMA ops ->
// s_waitcnt vmcnt(8) + raw barriers; K/V prefetch stays in flight across them.
__global__ __launch_bounds__(256)
void k_attn(const ushort* __restrict__ q, const ushort* __restrict__ k,
            const ushort* __restrict__ vt, float* __restrict__ out) {
    __shared__ short8 smem[81920 / 16];
    char* base = (char*)smem;                    // 2 x (K 16KB + V 16KB)
    char* pls  = base + 65536;                   // P: 4 waves x 4KB ([16][128] bf16)
    const int t = threadIdx.x, lane = t & 63, w = t >> 6;
    const int l15 = lane & 15, lg = lane >> 4;
    const int b = blockIdx.x & 15, qt = 31 - (blockIdx.x >> 4);  // heavy first
    const int row0 = qt * 64, r0w = row0 + w * 16;
    const ushort* qb = q  + (size_t)b * SEQ * HD;
    const ushort* kb = k  + (size_t)b * SEQ * HD;
    const ushort* vb = vt + (size_t)b * HD * SEQ;
    char* pw = pls + w * 4096;

    short8 qf[2];
    #pragma unroll
    for (int s = 0; s < 2; ++s)
        qf[s] = *(const short8*)&qb[(size_t)(r0w + l15) * HD + s * 32 + lg * 8];

    f32x4 oacc[4];
    #pragma unroll
    for (int h = 0; h < 4; ++h) oacc[h] = (f32x4){0.f, 0.f, 0.f, 0.f};
    float m_ = -INFINITY, l_ = 0.f;

    auto stage = [&](int kt, int buf) {          // 8 VMEM ops
        char* kbuf = base + buf * 32768;
        char* vbuf = kbuf + 16384;
        int k0 = kt * 128;
        #pragma unroll
        for (int g = 0; g < 4; ++g) {
            int rk = w * 32 + g * 8 + (lane >> 3);          // key row 0..127
            int jk = (lane & 7) ^ (rk & 7);
            gload_lds16(&kb[(size_t)(k0 + rk) * HD + jk * 8],
                        kbuf + (w * 4 + g) * 1024);
            int rv = w * 16 + g * 4 + (lane >> 4);          // hd row 0..63
            int jv = (lane & 15) ^ (rv & 15);
            gload_lds16(&vb[(size_t)rv * SEQ + k0 + jv * 8],
                        vbuf + (w * 4 + g) * 1024);
        }
    };

    const int npair = (qt + 2) >> 1;
    stage(0, 0);
    for (int kt = 0; kt < npair; ++kt) {
        int cur = kt & 1;
        if (kt + 1 < npair) {
            stage(kt + 1, cur ^ 1);
            asm volatile("s_waitcnt vmcnt(8)" ::: "memory");   // cur's DMAs landed
        } else {
            asm volatile("s_waitcnt vmcnt(0)" ::: "memory");
        }
        __builtin_amdgcn_sched_barrier(0);
        __builtin_amdgcn_s_barrier();            // BAR1: cross-wave DMA visibility
        char* kls = base + cur * 32768;
        char* vls = kls + 16384;
        int k0 = kt * 128;

        f32x4 sa[8];
        #pragma unroll
        for (int a = 0; a < 8; ++a) sa[a] = (f32x4){0.f, 0.f, 0.f, 0.f};
        __builtin_amdgcn_s_setprio(1);
        #pragma unroll
        for (int s = 0; s < 2; ++s)
            #pragma unroll
            for (int a = 0; a < 8; ++a) {
                int r = a * 16 + l15;
                short8 kf = *(short8*)(kls + SWZ(r * 128 + s * 64 + lg * 16, r));
                sa[a] = __builtin_amdgcn_mfma_f32_16x16x32_bf16(kf, qf[s], sa[a], 0, 0, 0);
            }
        __builtin_amdgcn_s_setprio(0);

        if (kt == npair - 1) {                   // causal mask (last pair only)
            int qrow = r0w + l15;
            #pragma unroll
            for (int a = 0; a < 8; ++a)
                #pragma unroll
                for (int r = 0; r < 4; ++r)
                    if (k0 + a * 16 + lg * 4 + r > qrow) sa[a][r] = -INFINITY;
        }

        float smax = -INFINITY;
        #pragma unroll
        for (int a = 0; a < 8; ++a)
            #pragma unroll
            for (int r = 0; r < 4; ++r) smax = fmaxf(smax, sa[a][r]);
        smax = fmaxf(smax, __shfl_xor(smax, 16));
        smax = fmaxf(smax, __shfl_xor(smax, 32));
        if (!__all(smax - m_ <= 8.0f)) {         // T13 defer-max
            float mn   = fmaxf(m_, smax);
            float corr = __builtin_amdgcn_exp2f(m_ - mn);
            l_ *= corr;
            #pragma unroll
            for (int h = 0; h < 4; ++h) oacc[h] *= corr;
            m_ = mn;
        }
        float p[32], ps = 0.f;
        #pragma unroll
        for (int a = 0; a < 8; ++a)
            #pragma unroll
            for (int r = 0; r < 4; ++r) {
                float pv = __builtin_amdgcn_exp2f(sa[a][r] - m_);
                p[a * 4 + r] = pv; ps += pv;
            }
        ps += __shfl_xor(ps, 16);
        ps += __shfl_xor(ps, 32);
        l_ += ps;

        #pragma unroll
        for (int a = 0; a < 8; ++a) {            // P -> per-wave LDS [16][128]
            ushort4 pb;
            pb.x = f2bf(p[a * 4 + 0]); pb.y = f2bf(p[a * 4 + 1]);
            pb.z = f2bf(p[a * 4 + 2]); pb.w = f2bf(p[a * 4 + 3]);
            *(ushort4*)(pw + SWZ16(l15 * 256 + a * 32 + lg * 8, l15)) = pb;
        }

        __builtin_amdgcn_s_setprio(1);
        #pragma unroll
        for (int ki = 0; ki < 4; ++ki) {         // PV over 128 keys
            short8 pf = *(short8*)(pw + SWZ16(l15 * 256 + ki * 64 + lg * 16, l15));
            #pragma unroll
            for (int h = 0; h < 4; ++h) {
                int rr = h * 16 + l15;
                short8 vf = *(short8*)(vls + SWZ16(rr * 256 + ki * 64 + lg * 16, rr));
                oacc[h] = __builtin_amdgcn_mfma_f32_16x16x32_bf16(vf, pf, oacc[h], 0, 0, 0);
            }
        }
        __builtin_amdgcn_s_setprio(0);
        __builtin_amdgcn_sched_barrier(0);
        __builtin_amdgcn_s_barrier();            // BAR2: readers done before overwrite
    }

    // epilogue: out via LDS transpose -> coalesced float4 stores
    float inv = 1.0f / l_;
    #pragma unroll
    for (int h = 0; h < 4; ++h) {
        f32x4 v = oacc[h] * inv;
        int qr = w * 16 + l15;
        *(f32x4*)(base + SWZ16(qr * 256 + h * 64 + lg * 16, qr)) = v;
    }
    __syncthreads();
    #pragma unroll
    for (int i = 0; i < 4; ++i) {
        int idx = t + i * 256;
        int r = idx >> 4, g = idx & 15;
        f32x4 v = *(f32x4*)(base + SWZ16(r * 256 + g * 16, r));
        *(f32x4*)&out[((size_t)b * SEQ + row0 + r) * HD + g * 4] = v;
    }
}

extern "C" void kernel_launch(void* const* d_in, const int* in_sizes, int n_in,
                              void* d_out, int out_size, void* d_ws, size_t ws_size,
                              hipStream_t stream) {
    const float* x  = (const float*)d_in[0];
    const float* Wq = (const float*)d_in[1];
    const float* Wk = (const float*)d_in[2];
    const float* Wv = (const float*)d_in[3];
    float* out = (float*)d_out;
    ushort* ws = (ushort*)d_ws;
    ushort* wt16 = ws;                                   // 192*1024
    ushort* qk16 = ws + 192 * 1024;                      // 2*NROWS*64 (Q,K)
    ushort* vt16 = qk16 + (size_t)2 * NROWS * HD;        // BATCH*64*2048

    k_transpose_w<<<768, 256, 0, stream>>>(Wq, Wk, Wv, wt16);
    k_qkv_proj  <<<NROWS / 64, 256, 0, stream>>>(x, wt16, qk16, vt16);
    k_attn      <<<BATCH * (SEQ / 64), 256, 0, stream>>>(
                    qk16, qk16 + (size_t)NROWS * HD, vt16, out);
}